// Round 19
// baseline (379.732 us; speedup 1.0000x reference)
//
#include <hip/hip_runtime.h>
#include <math.h>

typedef float  f32x4  __attribute__((ext_vector_type(4)));
typedef __bf16 bf16x8 __attribute__((ext_vector_type(8)));

union FragU { uint4 q; bf16x8 b; };

__device__ inline float fc(const float4& v, int k){
  return k==0 ? v.x : k==1 ? v.y : k==2 ? v.z : v.w;
}

// ---------- K0: pack weights to bf16 in MFMA B-fragment order ----------
// frag idx: (((ct*KS + ks)*64 + lane)*8 + j) ; k = ks*32 + (lane>>4)*8 + j ; c = ct*16 + (lane&15)
__global__ void k_pack(const float* __restrict__ Wl, const float* __restrict__ Wr,
                       const float* __restrict__ We, const float* __restrict__ Wm,
                       const float* __restrict__ lng, const float* __restrict__ lnb,
                       unsigned short* plr, unsigned short* pe, unsigned short* pm,
                       unsigned short* plnb){
  int t = blockIdx.x * 256 + threadIdx.x;
  if (t < 32768){
    int j = t & 7, lane = (t >> 3) & 63, ks = (t >> 9) & 3, ct = t >> 11;
    int k = ks*32 + (lane >> 4)*8 + j, c = ct*16 + (lane & 15);
    float v = (c < 128) ? Wl[k*128 + c] : Wr[k*128 + (c - 128)];
    __bf16 b = (__bf16)v; plr[t] = *(unsigned short*)&b;
  }
  if (t < 16384){
    int j = t & 7, lane = (t >> 3) & 63, ks = (t >> 9) & 3, ct = t >> 11;
    int k = ks*32 + (lane >> 4)*8 + j, c = ct*16 + (lane & 15);
    __bf16 b = (__bf16)We[k*128 + c]; pe[t] = *(unsigned short*)&b;
  }
  if (t < 32768){
    int j = t & 7, lane = (t >> 3) & 63, ks = (t >> 9) & 7, ct = t >> 12;
    int k = ks*32 + (lane >> 4)*8 + j, c = ct*16 + (lane & 15);
    __bf16 b = (__bf16)Wm[k*128 + c]; pm[t] = *(unsigned short*)&b;
  }
  if (t < 512){
    float v = (t < 256) ? lng[t] : lnb[t-256];
    __bf16 b = (__bf16)v; plnb[t] = *(unsigned short*)&b;
  }
}

// ---------- CSR build: hist -> 3-phase scan (payload written by k_edge_logits) ----------
__global__ void k_hist(const int* __restrict__ dst, int* __restrict__ cnt, int E){
  int e = blockIdx.x*256 + threadIdx.x;
  if (e < E) atomicAdd(&cnt[dst[e]], 1);
}

__global__ void k_scan1(const int* __restrict__ cnt, int* __restrict__ pre,
                        int* __restrict__ bsum, int n){
  __shared__ int wsum[4];
  int t = threadIdx.x, lane = t & 63, w = t >> 6;
  int base = blockIdx.x*1024 + t*4;
  int v[4]; int loc = 0;
  #pragma unroll
  for (int j = 0; j < 4; ++j){ v[j] = (base+j < n) ? cnt[base+j] : 0; loc += v[j]; }
  int incl = loc;
  #pragma unroll
  for (int o = 1; o < 64; o <<= 1){
    int u = __shfl_up(incl, o);
    if (lane >= o) incl += u;
  }
  if (lane == 63) wsum[w] = incl;
  __syncthreads();
  int wbase = 0;
  #pragma unroll
  for (int ww = 0; ww < 4; ++ww) if (ww < w) wbase += wsum[ww];
  int run = wbase + incl - loc;
  #pragma unroll
  for (int j = 0; j < 4; ++j){ if (base+j < n) pre[base+j] = run; run += v[j]; }
  if (t == 255) bsum[blockIdx.x] = wbase + incl;
}

__global__ void k_scan2(const int* __restrict__ bsum, int* __restrict__ boff, int nb){
  int t = threadIdx.x;
  int v = (t < nb) ? bsum[t] : 0;
  int incl = v;
  #pragma unroll
  for (int o = 1; o < 64; o <<= 1){
    int u = __shfl_up(incl, o);
    if (t >= o) incl += u;
  }
  if (t < nb) boff[t] = incl - v;
  if (t == nb-1) boff[nb] = incl;
}

__global__ void k_scan3(const int* __restrict__ pre, const int* __restrict__ boff,
                        int* __restrict__ rowptr, int* __restrict__ cursor, int n, int nb){
  int i = blockIdx.x*256 + threadIdx.x;
  if (i < n){
    int r = pre[i] + boff[blockIdx.x >> 2];
    rowptr[i] = r; cursor[i] = r;
  }
  if (i == 0) rowptr[n] = boff[nb];
}

// ---------- K1: xlxr = [x@W_l+b_l | x@W_r+b_r]  (MFMA), OUTPUT IN BF16 ----------
__launch_bounds__(512)
__global__ void k_node_linear(const float* __restrict__ x, const float* __restrict__ bl,
                              const float* __restrict__ br, const unsigned short* __restrict__ plr,
                              __bf16* __restrict__ xlxr, int n){
  __shared__ uint4 sW[4096];
  int t = threadIdx.x, lane = t & 63, w = t >> 6, lo = lane & 15, hi = lane >> 4;
  for (int i = t; i < 4096; i += 512) sW[i] = ((const uint4*)plr)[i];
  int row = blockIdx.x*128 + w*16 + lo;
  int rc  = min(row, n-1);
  bf16x8 A[4];
  #pragma unroll
  for (int ks = 0; ks < 4; ++ks){
    const float* p = &x[(size_t)rc*128 + ks*32 + hi*8];
    float4 v0 = *(const float4*)p, v1 = *(const float4*)(p+4);
    FragU u;
    u.b[0]=(__bf16)v0.x; u.b[1]=(__bf16)v0.y; u.b[2]=(__bf16)v0.z; u.b[3]=(__bf16)v0.w;
    u.b[4]=(__bf16)v1.x; u.b[5]=(__bf16)v1.y; u.b[6]=(__bf16)v1.z; u.b[7]=(__bf16)v1.w;
    A[ks] = u.b;
  }
  __syncthreads();
  f32x4 acc[16];
  #pragma unroll
  for (int ct = 0; ct < 16; ++ct) acc[ct] = (f32x4)(0.f);
  #pragma unroll
  for (int ks = 0; ks < 4; ++ks){
    #pragma unroll
    for (int ct = 0; ct < 16; ++ct){
      FragU bu; bu.q = sW[(ct*4 + ks)*64 + lane];
      acc[ct] = __builtin_amdgcn_mfma_f32_16x16x32_bf16(A[ks], bu.b, acc[ct], 0, 0, 0);
    }
  }
  float biasL[16];
  #pragma unroll
  for (int ct = 0; ct < 16; ++ct){
    int c = ct*16 + lo;
    biasL[ct] = (c < 128) ? bl[c] : br[c - 128];
  }
  #pragma unroll
  for (int j = 0; j < 4; ++j){
    int nd = blockIdx.x*128 + w*16 + hi*4 + j;
    if (nd < n){
      #pragma unroll
      for (int ct = 0; ct < 16; ++ct)
        xlxr[(size_t)nd*256 + ct*16 + lo] = (__bf16)(acc[ct][j] + biasL[ct]);
    }
  }
}

// ---------- K2: ee GEMM (MFMA) + attention logits + DIRECT CSR payload write ----------
// epilogue computes per-edge logits qh then (at lo==0): p = atomicAdd(cursor[d_]),
// elogp[p] = qh (16B), srcp[p] = s_. Kills the elog buffer + k_scatter round-trip.
__launch_bounds__(512)
__global__ void k_edge_logits(const float* __restrict__ eattr, const int* __restrict__ src,
                              const int* __restrict__ dst, const unsigned short* __restrict__ pe,
                              const float* __restrict__ be, const float* __restrict__ att,
                              const __bf16* __restrict__ xlxr, int* __restrict__ cursor,
                              float4* __restrict__ elogp, int* __restrict__ srcp, int E){
  __shared__ uint4 sW[2048];  // 32KB
  int t = threadIdx.x, lane = t & 63, w = t >> 6, lo = lane & 15, hi = lane >> 4;
  for (int i = t; i < 2048; i += 512) sW[i] = ((const uint4*)pe)[i];
  int eb = blockIdx.x*128 + w*16;
  int er = min(eb + lo, E-1);
  bf16x8 A[4];
  #pragma unroll
  for (int ks = 0; ks < 4; ++ks){
    const float* p = &eattr[(size_t)er*128 + ks*32 + hi*8];
    f32x4 v0 = __builtin_nontemporal_load((const f32x4*)p);
    f32x4 v1 = __builtin_nontemporal_load((const f32x4*)(p+4));
    FragU u;
    u.b[0]=(__bf16)v0[0]; u.b[1]=(__bf16)v0[1]; u.b[2]=(__bf16)v0[2]; u.b[3]=(__bf16)v0[3];
    u.b[4]=(__bf16)v1[0]; u.b[5]=(__bf16)v1[1]; u.b[6]=(__bf16)v1[2]; u.b[7]=(__bf16)v1[3];
    A[ks] = u.b;
  }
  __syncthreads();
  f32x4 acc[8];
  #pragma unroll
  for (int ct = 0; ct < 8; ++ct) acc[ct] = (f32x4)(0.f);
  #pragma unroll
  for (int ks = 0; ks < 4; ++ks){
    #pragma unroll
    for (int ct = 0; ct < 8; ++ct){
      FragU bu; bu.q = sW[(ct*4 + ks)*64 + lane];
      acc[ct] = __builtin_amdgcn_mfma_f32_16x16x32_bf16(A[ks], bu.b, acc[ct], 0, 0, 0);
    }
  }
  float beL[8], atL[8];
  #pragma unroll
  for (int ct = 0; ct < 8; ++ct){ beL[ct] = be[ct*16 + lo]; atL[ct] = att[ct*16 + lo]; }
  #pragma unroll
  for (int j = 0; j < 4; ++j){
    int e = eb + hi*4 + j;
    int ec = min(e, E-1);
    int s_ = src[ec], d_ = dst[ec];
    const __bf16* xlp = &xlxr[(size_t)s_*256];
    const __bf16* xrp = &xlxr[(size_t)d_*256 + 128];
    float qh[4];
    #pragma unroll
    for (int h = 0; h < 4; ++h){
      float p = 0.f;
      #pragma unroll
      for (int u = 0; u < 2; ++u){
        int ct = 2*h + u, c = ct*16 + lo;
        float m = acc[ct][j] + beL[ct] + (float)xlp[c] + (float)xrp[c];
        m = (m > 0.f) ? m : 0.2f*m;
        p = fmaf(m, atL[ct], p);
      }
      p += __shfl_xor(p, 1); p += __shfl_xor(p, 2);
      p += __shfl_xor(p, 4); p += __shfl_xor(p, 8);
      qh[h] = p;
    }
    if (lo == 0 && e < E){
      int p = atomicAdd(&cursor[d_], 1);
      elogp[p] = make_float4(qh[0], qh[1], qh[2], qh[3]);
      srcp[p]  = s_;
    }
  }
}

// ---------- K5: per-node segment softmax + aggregation + bias + LN partials ----------
// CSR-ordered payload: elogp[i]/srcp[i] directly indexed (wave-uniform broadcast
// loads, addresses known without dependent loads). Two col-chains per lane for ILP.
// Linear-in-alpha: pass1 pure fmax; pass2 independent exps; normalize once.
__launch_bounds__(256)
__global__ void k_gat_agg(const float4* __restrict__ elogp, const int* __restrict__ rowptr,
                          const int* __restrict__ srcp,
                          const __bf16* __restrict__ xlxr, const float* __restrict__ bias,
                          float* __restrict__ xnew, __bf16* __restrict__ xnb,
                          float2* __restrict__ nstat, int n){
  int nd = (blockIdx.x*256 + threadIdx.x) >> 6;
  int lane = threadIdx.x & 63;
  if (nd >= n) return;
  int beg = rowptr[nd], end = rowptr[nd+1];
  bool hsel = (lane & 32) != 0;
  // pass 1: pure max, 2-way unrolled (independent broadcast loads)
  float m0 = -INFINITY, m1 = -INFINITY;
  float m0b = -INFINITY, m1b = -INFINITY;
  int i = beg;
  for (; i + 1 < end; i += 2){
    float4 la = elogp[i], lb = elogp[i+1];
    float a0 = hsel ? la.y : la.x, a1 = hsel ? la.w : la.z;
    float b0 = hsel ? lb.y : lb.x, b1 = hsel ? lb.w : lb.z;
    m0 = fmaxf(m0, a0); m1 = fmaxf(m1, a1);
    m0b = fmaxf(m0b, b0); m1b = fmaxf(m1b, b1);
  }
  if (i < end){
    float4 la = elogp[i];
    m0 = fmaxf(m0, hsel ? la.y : la.x); m1 = fmaxf(m1, hsel ? la.w : la.z);
  }
  m0 = fmaxf(m0, m0b); m1 = fmaxf(m1, m1b);
  // pass 2: unnormalized exp-weighted aggregation + denom, 2-way unrolled
  float d0 = 0.f, d1 = 0.f, a0 = 0.f, a1 = 0.f;
  int c0 = lane, c1 = lane + 64;
  i = beg;
  for (; i + 1 < end; i += 2){
    float4 la = elogp[i], lb = elogp[i+1];
    int spA = srcp[i], spB = srcp[i+1];
    const __bf16* xpA = &xlxr[(size_t)spA*256];
    const __bf16* xpB = &xlxr[(size_t)spB*256];
    float xA0 = (float)xpA[c0], xA1 = (float)xpA[c1];
    float xB0 = (float)xpB[c0], xB1 = (float)xpB[c1];
    float eA0 = __expf((hsel ? la.y : la.x) - m0), eA1 = __expf((hsel ? la.w : la.z) - m1);
    float eB0 = __expf((hsel ? lb.y : lb.x) - m0), eB1 = __expf((hsel ? lb.w : lb.z) - m1);
    d0 += eA0 + eB0; d1 += eA1 + eB1;
    a0 = fmaf(eA0, xA0, a0); a0 = fmaf(eB0, xB0, a0);
    a1 = fmaf(eA1, xA1, a1); a1 = fmaf(eB1, xB1, a1);
  }
  if (i < end){
    float4 la = elogp[i];
    int sp = srcp[i];
    const __bf16* xp = &xlxr[(size_t)sp*256];
    float e0 = __expf((hsel ? la.y : la.x) - m0), e1 = __expf((hsel ? la.w : la.z) - m1);
    d0 += e0; d1 += e1;
    a0 = fmaf(e0, (float)xp[c0], a0);
    a1 = fmaf(e1, (float)xp[c1], a1);
  }
  float r0 = 1.f/(d0 + 1e-16f), r1 = 1.f/(d1 + 1e-16f);
  float v0 = fmaf(a0, r0, bias[c0]), v1 = fmaf(a1, r1, bias[c1]);
  xnew[(size_t)nd*128 + c0] = v0;
  xnew[(size_t)nd*128 + c1] = v1;
  xnb[(size_t)nd*128 + c0] = (__bf16)v0;
  xnb[(size_t)nd*128 + c1] = (__bf16)v1;
  float s  = v0 + v1;
  float ss = fmaf(v0, v0, v1*v1);
  #pragma unroll
  for (int o = 1; o < 64; o <<= 1){ s += __shfl_xor(s, o); ss += __shfl_xor(ss, o); }
  if (lane == 0) nstat[nd] = make_float2(s, ss);
}

// ---------- K7: edge MLP (MFMA), round-12/15 structure (proven) ----------
// 8 waves x 16 edges = 128 edges/block; 64KB W staged once; one barrier.
// eattr residual NT-prefetched in C-layout (16 lanes x 4B = 64B contiguous per row
// per instruction); gather is bf16 from xnb (8x uint4/lane).
__launch_bounds__(512, 4)
__global__ void k_edge_mlp(const __bf16* __restrict__ xnb, const int* __restrict__ src,
                           const int* __restrict__ dst, const float* __restrict__ eattr,
                           const unsigned short* __restrict__ pm, const float* __restrict__ bmlp,
                           const unsigned short* __restrict__ plnb,
                           const float2* __restrict__ nstat, float* __restrict__ out, int E){
  __shared__ uint4 sW[4096];                        // 64KB W_mlp fragments
  __shared__ __align__(16) unsigned short sLN[512]; // gamma(256) | beta(256), bf16
  const uint4* pm_q = (const uint4*)pm;
  int t = threadIdx.x, lane = t & 63, w = t >> 6, lo = lane & 15, hi = lane >> 4;
  int base = blockIdx.x*128;
  // (1) NT prefetch of eattr residual, C-fragment layout: row hi*4+j, col ct*16+lo
  float ev[4][8];
  #pragma unroll
  for (int j = 0; j < 4; ++j){
    int e2 = min(base + w*16 + hi*4 + j, E-1);
    const float* ep = &eattr[(size_t)e2*128 + lo];
    #pragma unroll
    for (int ct = 0; ct < 8; ++ct)
      ev[j][ct] = __builtin_nontemporal_load(ep + ct*16);
  }
  // (2) stage W + LN constants (overlaps prefetch + gather)
  for (int i = t; i < 4096; i += 512) sW[i] = pm_q[i];
  if (t < 512) sLN[t] = plnb[t];
  // (3) issue bf16 gather + LN stats (loads in flight across the barrier)
  int e  = base + w*16 + lo;
  int ec = min(e, E-1);
  int s_ = src[ec], d_ = dst[ec];
  float2 stS = nstat[s_], stD = nstat[d_];
  float mean = (stS.x + stD.x) * (1.f/256.f);
  float var  = (stS.y + stD.y) * (1.f/256.f) - mean*mean;
  float rstd = rsqrtf(var + 1e-5f);
  const __bf16* srow = &xnb[(size_t)s_*128 + hi*8];
  const __bf16* drow = &xnb[(size_t)d_*128 + hi*8];
  uint4 g[8];
  #pragma unroll
  for (int ks = 0; ks < 4; ++ks){
    g[ks]   = *(const uint4*)&srow[ks*32];
    g[4+ks] = *(const uint4*)&drow[ks*32];
  }
  __syncthreads();   // sW + sLN staged; gather loads drained by compiler waitcnt
  // (4) LN + ReLU -> bf16 A-frags (sLN read is safe post-barrier)
  bf16x8 af[8];
  #pragma unroll
  for (int ks = 0; ks < 8; ++ks){
    int cb = ks*32 + hi*8;
    FragU u, a, lg, lb;
    u.q  = g[ks];
    lg.q = *(const uint4*)&sLN[cb];
    lb.q = *(const uint4*)&sLN[256 + cb];
    #pragma unroll
    for (int j = 0; j < 8; ++j){
      float v = fmaxf(fmaf(((float)u.b[j] - mean)*rstd, (float)lg.b[j], (float)lb.b[j]), 0.f);
      a.b[j] = (__bf16)v;
    }
    af[ks] = a.b;
  }
  // (5) MFMA
  f32x4 acc[8];
  #pragma unroll
  for (int ct = 0; ct < 8; ++ct) acc[ct] = (f32x4)(0.f);
  #pragma unroll
  for (int ks = 0; ks < 8; ++ks){
    #pragma unroll
    for (int ct = 0; ct < 8; ++ct){
      FragU bu; bu.q = sW[(ct*8 + ks)*64 + lane];
      acc[ct] = __builtin_amdgcn_mfma_f32_16x16x32_bf16(af[ks], bu.b, acc[ct], 0, 0, 0);
    }
  }
  // (6) epilogue: residual from prefetched regs, NT stores (C-layout, coalesced 64B/row/instr)
  float bmL[8];
  #pragma unroll
  for (int ct = 0; ct < 8; ++ct) bmL[ct] = bmlp[ct*16 + lo];
  #pragma unroll
  for (int j = 0; j < 4; ++j){
    int e2 = base + w*16 + hi*4 + j;
    if (e2 < E){
      #pragma unroll
      for (int ct = 0; ct < 8; ++ct){
        int c = ct*16 + lo;
        __builtin_nontemporal_store(acc[ct][j] + bmL[ct] + ev[j][ct],
                                    &out[(size_t)e2*128 + c]);
      }
    }
  }
}

// ---------- launcher ----------
extern "C" void kernel_launch(void* const* d_in, const int* in_sizes, int n_in,
                              void* d_out, int out_size, void* d_ws, size_t ws_size,
                              hipStream_t stream){
  const float* x     = (const float*)d_in[0];
  const int*   eidx  = (const int*)  d_in[1];
  const float* eattr = (const float*)d_in[2];
  const float* Wl    = (const float*)d_in[3];
  const float* bl    = (const float*)d_in[4];
  const float* Wr    = (const float*)d_in[5];
  const float* br    = (const float*)d_in[6];
  const float* We    = (const float*)d_in[7];
  const float* be    = (const float*)d_in[8];
  const float* att   = (const float*)d_in[9];
  const float* bias  = (const float*)d_in[10];
  const float* lng   = (const float*)d_in[11];
  const float* lnb   = (const float*)d_in[12];
  const float* Wmlp  = (const float*)d_in[13];
  const float* bmlp  = (const float*)d_in[14];

  int n = in_sizes[0] / 128;
  int E = in_sizes[2] / 128;
  const int* src = eidx;
  const int* dst = eidx + E;
  int nb = (n + 1023) / 1024;

  char* ws = (char*)d_ws;
  size_t off = 0;
  int* cnt    = (int*)(ws + off); off += (size_t)n*4;
  size_t zbytes = off;                       // only cnt needs zeroing
  int* pre    = (int*)(ws + off); off += (size_t)n*4;
  int* rowptr = (int*)(ws + off); off += (size_t)(n+1)*4;
  int* cursor = (int*)(ws + off); off += (size_t)(n+1)*4;
  int* bsum   = (int*)(ws + off); off += (size_t)nb*4;
  int* boff   = (int*)(ws + off); off += (size_t)(nb+1)*4;
  off = (off + 15) & ~(size_t)15;
  float4* elogp = (float4*)(ws + off); off += (size_t)E*16;
  int* srcp   = (int*)(ws + off); off += (size_t)E*4;
  __bf16* xlxr = (__bf16*)(ws + off); off += (size_t)n*256*2;
  float2* nstat = (float2*)(ws + off); off += (size_t)n*8;
  __bf16* xnb = (__bf16*)(ws + off); off += (size_t)n*128*2;
  unsigned short* plr = (unsigned short*)(ws + off); off += 32768*2;
  unsigned short* pe  = (unsigned short*)(ws + off); off += 16384*2;
  unsigned short* pm  = (unsigned short*)(ws + off); off += 32768*2;
  unsigned short* plnb= (unsigned short*)(ws + off); off += 512*2;

  float* xnew_out = (float*)d_out;
  float* eout     = (float*)d_out + (size_t)n*128;

  hipMemsetAsync(ws, 0, zbytes, stream);
  k_pack       <<<128, 256, 0, stream>>>(Wl, Wr, We, Wmlp, lng, lnb, plr, pe, pm, plnb);
  k_hist       <<<(E + 255)/256, 256, 0, stream>>>(dst, cnt, E);
  k_scan1      <<<nb, 256, 0, stream>>>(cnt, pre, bsum, n);
  k_scan2      <<<1, 64, 0, stream>>>(bsum, boff, nb);
  k_scan3      <<<nb*4, 256, 0, stream>>>(pre, boff, rowptr, cursor, n, nb);
  k_node_linear<<<(n + 127)/128, 512, 0, stream>>>(x, bl, br, plr, xlxr, n);
  k_edge_logits<<<(E + 127)/128, 512, 0, stream>>>(eattr, src, dst, pe, be, att, xlxr, cursor, elogp, srcp, E);
  k_gat_agg    <<<(n + 3)/4, 256, 0, stream>>>(elogp, rowptr, srcp, xlxr, bias, xnew_out, xnb, nstat, n);
  k_edge_mlp   <<<(E + 127)/128, 512, 0, stream>>>(xnb, src, dst, eattr, pm, bmlp, plnb, nstat, eout, E);
}

// Round 20
// 373.907 us; speedup vs baseline: 1.0156x; 1.0156x over previous
//
#include <hip/hip_runtime.h>
#include <math.h>

typedef float  f32x4  __attribute__((ext_vector_type(4)));
typedef __bf16 bf16x8 __attribute__((ext_vector_type(8)));

union FragU { uint4 q; bf16x8 b; };

__device__ inline float fc(const float4& v, int k){
  return k==0 ? v.x : k==1 ? v.y : k==2 ? v.z : v.w;
}

// ---------- K0: pack weights to bf16 in MFMA B-fragment order ----------
// frag idx: (((ct*KS + ks)*64 + lane)*8 + j) ; k = ks*32 + (lane>>4)*8 + j ; c = ct*16 + (lane&15)
__global__ void k_pack(const float* __restrict__ Wl, const float* __restrict__ Wr,
                       const float* __restrict__ We, const float* __restrict__ Wm,
                       const float* __restrict__ lng, const float* __restrict__ lnb,
                       unsigned short* plr, unsigned short* pe, unsigned short* pm,
                       unsigned short* plnb){
  int t = blockIdx.x * 256 + threadIdx.x;
  if (t < 32768){
    int j = t & 7, lane = (t >> 3) & 63, ks = (t >> 9) & 3, ct = t >> 11;
    int k = ks*32 + (lane >> 4)*8 + j, c = ct*16 + (lane & 15);
    float v = (c < 128) ? Wl[k*128 + c] : Wr[k*128 + (c - 128)];
    __bf16 b = (__bf16)v; plr[t] = *(unsigned short*)&b;
  }
  if (t < 16384){
    int j = t & 7, lane = (t >> 3) & 63, ks = (t >> 9) & 3, ct = t >> 11;
    int k = ks*32 + (lane >> 4)*8 + j, c = ct*16 + (lane & 15);
    __bf16 b = (__bf16)We[k*128 + c]; pe[t] = *(unsigned short*)&b;
  }
  if (t < 32768){
    int j = t & 7, lane = (t >> 3) & 63, ks = (t >> 9) & 7, ct = t >> 12;
    int k = ks*32 + (lane >> 4)*8 + j, c = ct*16 + (lane & 15);
    __bf16 b = (__bf16)Wm[k*128 + c]; pm[t] = *(unsigned short*)&b;
  }
  if (t < 512){
    float v = (t < 256) ? lng[t] : lnb[t-256];
    __bf16 b = (__bf16)v; plnb[t] = *(unsigned short*)&b;
  }
}

// ---------- CSR build: (hist fused into k_edge_logits) -> 3-phase scan -> payload scatter ----------
__global__ void k_scan1(const int* __restrict__ cnt, int* __restrict__ pre,
                        int* __restrict__ bsum, int n){
  __shared__ int wsum[4];
  int t = threadIdx.x, lane = t & 63, w = t >> 6;
  int base = blockIdx.x*1024 + t*4;
  int v[4]; int loc = 0;
  #pragma unroll
  for (int j = 0; j < 4; ++j){ v[j] = (base+j < n) ? cnt[base+j] : 0; loc += v[j]; }
  int incl = loc;
  #pragma unroll
  for (int o = 1; o < 64; o <<= 1){
    int u = __shfl_up(incl, o);
    if (lane >= o) incl += u;
  }
  if (lane == 63) wsum[w] = incl;
  __syncthreads();
  int wbase = 0;
  #pragma unroll
  for (int ww = 0; ww < 4; ++ww) if (ww < w) wbase += wsum[ww];
  int run = wbase + incl - loc;
  #pragma unroll
  for (int j = 0; j < 4; ++j){ if (base+j < n) pre[base+j] = run; run += v[j]; }
  if (t == 255) bsum[blockIdx.x] = wbase + incl;
}

__global__ void k_scan2(const int* __restrict__ bsum, int* __restrict__ boff, int nb){
  int t = threadIdx.x;
  int v = (t < nb) ? bsum[t] : 0;
  int incl = v;
  #pragma unroll
  for (int o = 1; o < 64; o <<= 1){
    int u = __shfl_up(incl, o);
    if (t >= o) incl += u;
  }
  if (t < nb) boff[t] = incl - v;
  if (t == nb-1) boff[nb] = incl;
}

__global__ void k_scan3(const int* __restrict__ pre, const int* __restrict__ boff,
                        int* __restrict__ rowptr, int* __restrict__ cursor, int n, int nb){
  int i = blockIdx.x*256 + threadIdx.x;
  if (i < n){
    int r = pre[i] + boff[blockIdx.x >> 2];
    rowptr[i] = r; cursor[i] = r;
  }
  if (i == 0) rowptr[n] = boff[nb];
}

// scatter edge payload into CSR order: elogp[p] = elog[e] (16B), srcp[p] = src[e].
// Sequential reads; one random 20B write per edge. Removes the eids->elog->src
// dependent-load chain from k_gat_agg entirely.
__global__ void k_scatter(const int* __restrict__ dst, const int* __restrict__ src,
                          const float* __restrict__ elog, int* __restrict__ cursor,
                          float4* __restrict__ elogp, int* __restrict__ srcp, int E){
  int e = blockIdx.x*256 + threadIdx.x;
  if (e < E){
    int p = atomicAdd(&cursor[dst[e]], 1);
    elogp[p] = *(const float4*)&elog[(size_t)e*4];
    srcp[p]  = src[e];
  }
}

// ---------- K1: xlxr = [x@W_l+b_l | x@W_r+b_r]  (MFMA), OUTPUT IN BF16 ----------
__launch_bounds__(512)
__global__ void k_node_linear(const float* __restrict__ x, const float* __restrict__ bl,
                              const float* __restrict__ br, const unsigned short* __restrict__ plr,
                              __bf16* __restrict__ xlxr, int n){
  __shared__ uint4 sW[4096];
  int t = threadIdx.x, lane = t & 63, w = t >> 6, lo = lane & 15, hi = lane >> 4;
  for (int i = t; i < 4096; i += 512) sW[i] = ((const uint4*)plr)[i];
  int row = blockIdx.x*128 + w*16 + lo;
  int rc  = min(row, n-1);
  bf16x8 A[4];
  #pragma unroll
  for (int ks = 0; ks < 4; ++ks){
    const float* p = &x[(size_t)rc*128 + ks*32 + hi*8];
    float4 v0 = *(const float4*)p, v1 = *(const float4*)(p+4);
    FragU u;
    u.b[0]=(__bf16)v0.x; u.b[1]=(__bf16)v0.y; u.b[2]=(__bf16)v0.z; u.b[3]=(__bf16)v0.w;
    u.b[4]=(__bf16)v1.x; u.b[5]=(__bf16)v1.y; u.b[6]=(__bf16)v1.z; u.b[7]=(__bf16)v1.w;
    A[ks] = u.b;
  }
  __syncthreads();
  f32x4 acc[16];
  #pragma unroll
  for (int ct = 0; ct < 16; ++ct) acc[ct] = (f32x4)(0.f);
  #pragma unroll
  for (int ks = 0; ks < 4; ++ks){
    #pragma unroll
    for (int ct = 0; ct < 16; ++ct){
      FragU bu; bu.q = sW[(ct*4 + ks)*64 + lane];
      acc[ct] = __builtin_amdgcn_mfma_f32_16x16x32_bf16(A[ks], bu.b, acc[ct], 0, 0, 0);
    }
  }
  float biasL[16];
  #pragma unroll
  for (int ct = 0; ct < 16; ++ct){
    int c = ct*16 + lo;
    biasL[ct] = (c < 128) ? bl[c] : br[c - 128];
  }
  #pragma unroll
  for (int j = 0; j < 4; ++j){
    int nd = blockIdx.x*128 + w*16 + hi*4 + j;
    if (nd < n){
      #pragma unroll
      for (int ct = 0; ct < 16; ++ct)
        xlxr[(size_t)nd*256 + ct*16 + lo] = (__bf16)(acc[ct][j] + biasL[ct]);
    }
  }
}

// ---------- K2: ee GEMM (MFMA) + attention logits + fused dst-histogram ----------
__launch_bounds__(512)
__global__ void k_edge_logits(const float* __restrict__ eattr, const int* __restrict__ src,
                              const int* __restrict__ dst, const unsigned short* __restrict__ pe,
                              const float* __restrict__ be, const float* __restrict__ att,
                              const __bf16* __restrict__ xlxr, float* __restrict__ elog,
                              int* __restrict__ cnt, int E){
  __shared__ uint4 sW[2048];  // 32KB
  int t = threadIdx.x, lane = t & 63, w = t >> 6, lo = lane & 15, hi = lane >> 4;
  for (int i = t; i < 2048; i += 512) sW[i] = ((const uint4*)pe)[i];
  int eb = blockIdx.x*128 + w*16;
  int er = min(eb + lo, E-1);
  bf16x8 A[4];
  #pragma unroll
  for (int ks = 0; ks < 4; ++ks){
    const float* p = &eattr[(size_t)er*128 + ks*32 + hi*8];
    f32x4 v0 = __builtin_nontemporal_load((const f32x4*)p);
    f32x4 v1 = __builtin_nontemporal_load((const f32x4*)(p+4));
    FragU u;
    u.b[0]=(__bf16)v0[0]; u.b[1]=(__bf16)v0[1]; u.b[2]=(__bf16)v0[2]; u.b[3]=(__bf16)v0[3];
    u.b[4]=(__bf16)v1[0]; u.b[5]=(__bf16)v1[1]; u.b[6]=(__bf16)v1[2]; u.b[7]=(__bf16)v1[3];
    A[ks] = u.b;
  }
  __syncthreads();
  f32x4 acc[8];
  #pragma unroll
  for (int ct = 0; ct < 8; ++ct) acc[ct] = (f32x4)(0.f);
  #pragma unroll
  for (int ks = 0; ks < 4; ++ks){
    #pragma unroll
    for (int ct = 0; ct < 8; ++ct){
      FragU bu; bu.q = sW[(ct*4 + ks)*64 + lane];
      acc[ct] = __builtin_amdgcn_mfma_f32_16x16x32_bf16(A[ks], bu.b, acc[ct], 0, 0, 0);
    }
  }
  float beL[8], atL[8];
  #pragma unroll
  for (int ct = 0; ct < 8; ++ct){ beL[ct] = be[ct*16 + lo]; atL[ct] = att[ct*16 + lo]; }
  #pragma unroll
  for (int j = 0; j < 4; ++j){
    int e = eb + hi*4 + j;
    int ec = min(e, E-1);
    int s_ = src[ec], d_ = dst[ec];
    const __bf16* xlp = &xlxr[(size_t)s_*256];
    const __bf16* xrp = &xlxr[(size_t)d_*256 + 128];
    float qh[4];
    #pragma unroll
    for (int h = 0; h < 4; ++h){
      float p = 0.f;
      #pragma unroll
      for (int u = 0; u < 2; ++u){
        int ct = 2*h + u, c = ct*16 + lo;
        float m = acc[ct][j] + beL[ct] + (float)xlp[c] + (float)xrp[c];
        m = (m > 0.f) ? m : 0.2f*m;
        p = fmaf(m, atL[ct], p);
      }
      p += __shfl_xor(p, 1); p += __shfl_xor(p, 2);
      p += __shfl_xor(p, 4); p += __shfl_xor(p, 8);
      qh[h] = p;
    }
    if (lo == 0 && e < E){
      *(float4*)&elog[(size_t)e*4] = make_float4(qh[0], qh[1], qh[2], qh[3]);
      atomicAdd(&cnt[d_], 1);   // fused histogram (each edge counted once)
    }
  }
}

// ---------- K5: per-node segment softmax + aggregation + bias + LN partials ----------
// CSR-ordered payload: elogp[i]/srcp[i] directly indexed (wave-uniform broadcast
// loads, addresses known without dependent loads). Two col-chains per lane for ILP.
// Linear-in-alpha: pass1 pure fmax; pass2 independent exps; normalize once.
__launch_bounds__(256)
__global__ void k_gat_agg(const float4* __restrict__ elogp, const int* __restrict__ rowptr,
                          const int* __restrict__ srcp,
                          const __bf16* __restrict__ xlxr, const float* __restrict__ bias,
                          float* __restrict__ xnew, __bf16* __restrict__ xnb,
                          float2* __restrict__ nstat, int n){
  int nd = (blockIdx.x*256 + threadIdx.x) >> 6;
  int lane = threadIdx.x & 63;
  if (nd >= n) return;
  int beg = rowptr[nd], end = rowptr[nd+1];
  bool hsel = (lane & 32) != 0;
  // pass 1: pure max, 2-way unrolled (independent broadcast loads)
  float m0 = -INFINITY, m1 = -INFINITY;
  float m0b = -INFINITY, m1b = -INFINITY;
  int i = beg;
  for (; i + 1 < end; i += 2){
    float4 la = elogp[i], lb = elogp[i+1];
    float a0 = hsel ? la.y : la.x, a1 = hsel ? la.w : la.z;
    float b0 = hsel ? lb.y : lb.x, b1 = hsel ? lb.w : lb.z;
    m0 = fmaxf(m0, a0); m1 = fmaxf(m1, a1);
    m0b = fmaxf(m0b, b0); m1b = fmaxf(m1b, b1);
  }
  if (i < end){
    float4 la = elogp[i];
    m0 = fmaxf(m0, hsel ? la.y : la.x); m1 = fmaxf(m1, hsel ? la.w : la.z);
  }
  m0 = fmaxf(m0, m0b); m1 = fmaxf(m1, m1b);
  // pass 2: unnormalized exp-weighted aggregation + denom, 2-way unrolled
  float d0 = 0.f, d1 = 0.f, a0 = 0.f, a1 = 0.f;
  int c0 = lane, c1 = lane + 64;
  i = beg;
  for (; i + 1 < end; i += 2){
    float4 la = elogp[i], lb = elogp[i+1];
    int spA = srcp[i], spB = srcp[i+1];
    const __bf16* xpA = &xlxr[(size_t)spA*256];
    const __bf16* xpB = &xlxr[(size_t)spB*256];
    float xA0 = (float)xpA[c0], xA1 = (float)xpA[c1];
    float xB0 = (float)xpB[c0], xB1 = (float)xpB[c1];
    float eA0 = __expf((hsel ? la.y : la.x) - m0), eA1 = __expf((hsel ? la.w : la.z) - m1);
    float eB0 = __expf((hsel ? lb.y : lb.x) - m0), eB1 = __expf((hsel ? lb.w : lb.z) - m1);
    d0 += eA0 + eB0; d1 += eA1 + eB1;
    a0 = fmaf(eA0, xA0, a0); a0 = fmaf(eB0, xB0, a0);
    a1 = fmaf(eA1, xA1, a1); a1 = fmaf(eB1, xB1, a1);
  }
  if (i < end){
    float4 la = elogp[i];
    int sp = srcp[i];
    const __bf16* xp = &xlxr[(size_t)sp*256];
    float e0 = __expf((hsel ? la.y : la.x) - m0), e1 = __expf((hsel ? la.w : la.z) - m1);
    d0 += e0; d1 += e1;
    a0 = fmaf(e0, (float)xp[c0], a0);
    a1 = fmaf(e1, (float)xp[c1], a1);
  }
  float r0 = 1.f/(d0 + 1e-16f), r1 = 1.f/(d1 + 1e-16f);
  float v0 = fmaf(a0, r0, bias[c0]), v1 = fmaf(a1, r1, bias[c1]);
  xnew[(size_t)nd*128 + c0] = v0;
  xnew[(size_t)nd*128 + c1] = v1;
  xnb[(size_t)nd*128 + c0] = (__bf16)v0;
  xnb[(size_t)nd*128 + c1] = (__bf16)v1;
  float s  = v0 + v1;
  float ss = fmaf(v0, v0, v1*v1);
  #pragma unroll
  for (int o = 1; o < 64; o <<= 1){ s += __shfl_xor(s, o); ss += __shfl_xor(ss, o); }
  if (lane == 0) nstat[nd] = make_float2(s, ss);
}

// ---------- K7: edge MLP (MFMA), round-12/15 structure (proven) ----------
// 8 waves x 16 edges = 128 edges/block; 64KB W staged once; one barrier.
// eattr residual NT-prefetched in C-layout (16 lanes x 4B = 64B contiguous per row
// per instruction); gather is bf16 from xnb (8x uint4/lane).
__launch_bounds__(512, 4)
__global__ void k_edge_mlp(const __bf16* __restrict__ xnb, const int* __restrict__ src,
                           const int* __restrict__ dst, const float* __restrict__ eattr,
                           const unsigned short* __restrict__ pm, const float* __restrict__ bmlp,
                           const unsigned short* __restrict__ plnb,
                           const float2* __restrict__ nstat, float* __restrict__ out, int E){
  __shared__ uint4 sW[4096];                        // 64KB W_mlp fragments
  __shared__ __align__(16) unsigned short sLN[512]; // gamma(256) | beta(256), bf16
  const uint4* pm_q = (const uint4*)pm;
  int t = threadIdx.x, lane = t & 63, w = t >> 6, lo = lane & 15, hi = lane >> 4;
  int base = blockIdx.x*128;
  // (1) NT prefetch of eattr residual, C-fragment layout: row hi*4+j, col ct*16+lo
  float ev[4][8];
  #pragma unroll
  for (int j = 0; j < 4; ++j){
    int e2 = min(base + w*16 + hi*4 + j, E-1);
    const float* ep = &eattr[(size_t)e2*128 + lo];
    #pragma unroll
    for (int ct = 0; ct < 8; ++ct)
      ev[j][ct] = __builtin_nontemporal_load(ep + ct*16);
  }
  // (2) stage W + LN constants (overlaps prefetch + gather)
  for (int i = t; i < 4096; i += 512) sW[i] = pm_q[i];
  if (t < 512) sLN[t] = plnb[t];
  // (3) issue bf16 gather + LN stats (loads in flight across the barrier)
  int e  = base + w*16 + lo;
  int ec = min(e, E-1);
  int s_ = src[ec], d_ = dst[ec];
  float2 stS = nstat[s_], stD = nstat[d_];
  float mean = (stS.x + stD.x) * (1.f/256.f);
  float var  = (stS.y + stD.y) * (1.f/256.f) - mean*mean;
  float rstd = rsqrtf(var + 1e-5f);
  const __bf16* srow = &xnb[(size_t)s_*128 + hi*8];
  const __bf16* drow = &xnb[(size_t)d_*128 + hi*8];
  uint4 g[8];
  #pragma unroll
  for (int ks = 0; ks < 4; ++ks){
    g[ks]   = *(const uint4*)&srow[ks*32];
    g[4+ks] = *(const uint4*)&drow[ks*32];
  }
  __syncthreads();   // sW + sLN staged; gather loads drained by compiler waitcnt
  // (4) LN + ReLU -> bf16 A-frags (sLN read is safe post-barrier)
  bf16x8 af[8];
  #pragma unroll
  for (int ks = 0; ks < 8; ++ks){
    int cb = ks*32 + hi*8;
    FragU u, a, lg, lb;
    u.q  = g[ks];
    lg.q = *(const uint4*)&sLN[cb];
    lb.q = *(const uint4*)&sLN[256 + cb];
    #pragma unroll
    for (int j = 0; j < 8; ++j){
      float v = fmaxf(fmaf(((float)u.b[j] - mean)*rstd, (float)lg.b[j], (float)lb.b[j]), 0.f);
      a.b[j] = (__bf16)v;
    }
    af[ks] = a.b;
  }
  // (5) MFMA
  f32x4 acc[8];
  #pragma unroll
  for (int ct = 0; ct < 8; ++ct) acc[ct] = (f32x4)(0.f);
  #pragma unroll
  for (int ks = 0; ks < 8; ++ks){
    #pragma unroll
    for (int ct = 0; ct < 8; ++ct){
      FragU bu; bu.q = sW[(ct*8 + ks)*64 + lane];
      acc[ct] = __builtin_amdgcn_mfma_f32_16x16x32_bf16(af[ks], bu.b, acc[ct], 0, 0, 0);
    }
  }
  // (6) epilogue: residual from prefetched regs, NT stores (C-layout, coalesced 64B/row/instr)
  float bmL[8];
  #pragma unroll
  for (int ct = 0; ct < 8; ++ct) bmL[ct] = bmlp[ct*16 + lo];
  #pragma unroll
  for (int j = 0; j < 4; ++j){
    int e2 = base + w*16 + hi*4 + j;
    if (e2 < E){
      #pragma unroll
      for (int ct = 0; ct < 8; ++ct){
        int c = ct*16 + lo;
        __builtin_nontemporal_store(acc[ct][j] + bmL[ct] + ev[j][ct],
                                    &out[(size_t)e2*128 + c]);
      }
    }
  }
}

// ---------- launcher ----------
extern "C" void kernel_launch(void* const* d_in, const int* in_sizes, int n_in,
                              void* d_out, int out_size, void* d_ws, size_t ws_size,
                              hipStream_t stream){
  const float* x     = (const float*)d_in[0];
  const int*   eidx  = (const int*)  d_in[1];
  const float* eattr = (const float*)d_in[2];
  const float* Wl    = (const float*)d_in[3];
  const float* bl    = (const float*)d_in[4];
  const float* Wr    = (const float*)d_in[5];
  const float* br    = (const float*)d_in[6];
  const float* We    = (const float*)d_in[7];
  const float* be    = (const float*)d_in[8];
  const float* att   = (const float*)d_in[9];
  const float* bias  = (const float*)d_in[10];
  const float* lng   = (const float*)d_in[11];
  const float* lnb   = (const float*)d_in[12];
  const float* Wmlp  = (const float*)d_in[13];
  const float* bmlp  = (const float*)d_in[14];

  int n = in_sizes[0] / 128;
  int E = in_sizes[2] / 128;
  const int* src = eidx;
  const int* dst = eidx + E;
  int nb = (n + 1023) / 1024;

  char* ws = (char*)d_ws;
  size_t off = 0;
  int* cnt    = (int*)(ws + off); off += (size_t)n*4;
  size_t zbytes = off;                       // only cnt needs zeroing
  int* pre    = (int*)(ws + off); off += (size_t)n*4;
  int* rowptr = (int*)(ws + off); off += (size_t)(n+1)*4;
  int* cursor = (int*)(ws + off); off += (size_t)(n+1)*4;
  int* bsum   = (int*)(ws + off); off += (size_t)nb*4;
  int* boff   = (int*)(ws + off); off += (size_t)(nb+1)*4;
  off = (off + 15) & ~(size_t)15;
  float4* elogp = (float4*)(ws + off); off += (size_t)E*16;
  int* srcp   = (int*)(ws + off); off += (size_t)E*4;
  __bf16* xlxr = (__bf16*)(ws + off); off += (size_t)n*256*2;
  float* elog = (float*)(ws + off); off += (size_t)E*4*4;
  float2* nstat = (float2*)(ws + off); off += (size_t)n*8;
  __bf16* xnb = (__bf16*)(ws + off); off += (size_t)n*128*2;
  unsigned short* plr = (unsigned short*)(ws + off); off += 32768*2;
  unsigned short* pe  = (unsigned short*)(ws + off); off += 16384*2;
  unsigned short* pm  = (unsigned short*)(ws + off); off += 32768*2;
  unsigned short* plnb= (unsigned short*)(ws + off); off += 512*2;

  float* xnew_out = (float*)d_out;
  float* eout     = (float*)d_out + (size_t)n*128;

  hipMemsetAsync(ws, 0, zbytes, stream);
  k_pack       <<<128, 256, 0, stream>>>(Wl, Wr, We, Wmlp, lng, lnb, plr, pe, pm, plnb);
  k_node_linear<<<(n + 127)/128, 512, 0, stream>>>(x, bl, br, plr, xlxr, n);
  k_edge_logits<<<(E + 127)/128, 512, 0, stream>>>(eattr, src, dst, pe, be, att, xlxr, elog, cnt, E);
  k_scan1      <<<nb, 256, 0, stream>>>(cnt, pre, bsum, n);
  k_scan2      <<<1, 64, 0, stream>>>(bsum, boff, nb);
  k_scan3      <<<nb*4, 256, 0, stream>>>(pre, boff, rowptr, cursor, n, nb);
  k_scatter    <<<(E + 255)/256, 256, 0, stream>>>(dst, src, elog, cursor, elogp, srcp, E);
  k_gat_agg    <<<(n + 3)/4, 256, 0, stream>>>(elogp, rowptr, srcp, xlxr, bias, xnew_out, xnb, nstat, n);
  k_edge_mlp   <<<(E + 127)/128, 512, 0, stream>>>(xnb, src, dst, eattr, pm, bmlp, plnb, nstat, eout, E);
}